// Round 3
// baseline (684.563 us; speedup 1.0000x reference)
//
#include <hip/hip_runtime.h>
#include <math.h>

// Problem constants (fixed by setup_inputs)
constexpr int Bc  = 32;     // batch
constexpr int Dc  = 256;    // word feature dim
constexpr int Tc  = 32;     // seq len
constexpr int DHc = 128;    // image feature dim
constexpr int Nc  = 16384;  // H*W = 128*128

typedef _Float16 v8hf __attribute__((ext_vector_type(8)));
typedef _Float16 v2hf __attribute__((ext_vector_type(2)));
typedef float    v4f  __attribute__((ext_vector_type(4)));

// ---------------------------------------------------------------------------
// Stage 1 (rewritten): V = W·wf_b + bias, emitted DIRECTLY as split-f16
// buffers in the layouts attn staging wants:
//   vth [b][t][k]  (f16 hi)   vtl [b][t][k]  (f16 lo)   vph [b][k][t] (f16 hi)
// grid: 32 b × 8 k-blocks of 16 = 256 blocks (1/CU), 256 threads.
// ---------------------------------------------------------------------------
__global__ __launch_bounds__(256) void values_kernel(
    const float* __restrict__ wf, const float* __restrict__ Wm,
    const float* __restrict__ bias,
    _Float16* __restrict__ vth, _Float16* __restrict__ vtl,
    _Float16* __restrict__ vph)
{
    __shared__ float wfs[Dc * Tc];        // 32 KB  [d][t]
    __shared__ float Ws[16 * 260];        // 16.6 KB, padded rows (260) vs bank stride

    const int tid = threadIdx.x;
    const int b   = blockIdx.x >> 3;
    const int k0  = (blockIdx.x & 7) * 16;

    {   // stage wf[b]: 8192 floats, coalesced float4
        const float4* src = (const float4*)(wf + (size_t)b * Dc * Tc);
        float4* dst = (float4*)wfs;
        #pragma unroll
        for (int i = 0; i < 8; ++i) dst[tid + 256 * i] = src[tid + 256 * i];
    }
    {   // stage W rows k0..k0+15: 4096 floats
        #pragma unroll
        for (int i = 0; i < 4; ++i) {
            int f = tid + 256 * i;            // float4 index
            int row = f >> 6, d4 = f & 63;
            *(float4*)&Ws[row * 260 + 4 * d4] =
                *(const float4*)&Wm[(size_t)(k0 + row) * Dc + 4 * d4];
        }
    }
    __syncthreads();

    const int kl  = tid >> 4;          // 0..15
    const int tt0 = (tid & 15) * 2;    // even t
    const int k   = k0 + kl;

    float acc0 = bias[k], acc1 = acc0;
    #pragma unroll
    for (int d4 = 0; d4 < 64; ++d4) {
        const float4 w4 = *(const float4*)&Ws[kl * 260 + 4 * d4];
        #pragma unroll
        for (int j = 0; j < 4; ++j) {
            const float2 f2 = *(const float2*)&wfs[(4 * d4 + j) * Tc + tt0];
            const float wv = (j == 0) ? w4.x : (j == 1) ? w4.y : (j == 2) ? w4.z : w4.w;
            acc0 = fmaf(wv, f2.x, acc0);
            acc1 = fmaf(wv, f2.y, acc1);
        }
    }

    _Float16 vh0 = (_Float16)acc0, vh1 = (_Float16)acc1;
    _Float16 vl0 = (_Float16)(acc0 - (float)vh0);
    _Float16 vl1 = (_Float16)(acc1 - (float)vh1);

    // vph [b][k][t]: two halves at tt0 (4B aligned)
    {
        v2hf p; p[0] = vh0; p[1] = vh1;
        *(v2hf*)&vph[((size_t)b * DHc + k) * Tc + tt0] = p;
    }
    // vth/vtl [b][t][k]
    vth[((size_t)b * Tc + tt0)     * DHc + k] = vh0;
    vth[((size_t)b * Tc + tt0 + 1) * DHc + k] = vh1;
    vtl[((size_t)b * Tc + tt0)     * DHc + k] = vl0;
    vtl[((size_t)b * Tc + tt0 + 1) * DHc + k] = vl1;
}

__device__ __forceinline__ _Float16 pick_half(int u, int sel) {
    unsigned short s = (unsigned short)(sel ? (u >> 16) : u);
    return __builtin_bit_cast(_Float16, s);
}

// ---------------------------------------------------------------------------
// Stage 2 (MFMA): per 512-pixel strip of one batch.
//  staging = pure uint4 copies of pre-split V
//  Sᵀ = Vᵀ·Q (f16 hi/lo 3-term split), in-register masked softmax,
//  P relayout via shuffles, Oᵀ = Pᵀ·Vhᵀ with dwordx4 stores.
//  Q loads software-pipelined one iteration ahead.
// ---------------------------------------------------------------------------
__global__ __launch_bounds__(256, 4) void attn_kernel(
    const float* __restrict__ img,
    const _Float16* __restrict__ vth, const _Float16* __restrict__ vtl,
    const _Float16* __restrict__ vph,
    const int* __restrict__ mask, float* __restrict__ attn,
    float* __restrict__ coeff)
{
    constexpr int VT_LD = 136;  // k-stride (halves); 272B rows
    constexpr int VP_LD = 40;   // t-stride (halves); 80B rows
    __shared__ __align__(16) _Float16 VTh[Tc * VT_LD];
    __shared__ __align__(16) _Float16 VTl[Tc * VT_LD];
    __shared__ __align__(16) _Float16 VPh[DHc * VP_LD];
    __shared__ float mneg[Tc];

    const int tid   = threadIdx.x;
    const int b     = blockIdx.x >> 5;
    const int strip = blockIdx.x & 31;

    {   // staging: pure copies (512 chunks of 16B per buffer)
        const uint4* sth = (const uint4*)(vth + (size_t)b * Tc * DHc);
        const uint4* stl = (const uint4*)(vtl + (size_t)b * Tc * DHc);
        const uint4* sph = (const uint4*)(vph + (size_t)b * DHc * Tc);
        #pragma unroll
        for (int i = 0; i < 2; ++i) {
            int cid = tid + 256 * i;
            int t = cid >> 4, cc = cid & 15;        // 16 chunks per 128-half row
            *(uint4*)&VTh[t * VT_LD + 8 * cc] = sth[cid];
            *(uint4*)&VTl[t * VT_LD + 8 * cc] = stl[cid];
            int kk = cid >> 2, c4 = cid & 3;        // 4 chunks per 32-half row
            *(uint4*)&VPh[kk * VP_LD + 8 * c4] = sph[cid];
        }
        if (tid < Tc) mneg[tid] = mask[b * Tc + tid] ? -INFINITY : 0.0f;
    }
    __syncthreads();

    const int lane = tid & 63;
    const int wave = tid >> 6;
    const int c    = lane & 15;   // pixel column within 16-px tile
    const int g    = lane >> 4;   // lane group

    float madd[2][4];
    #pragma unroll
    for (int tt = 0; tt < 2; ++tt)
        #pragma unroll
        for (int r = 0; r < 4; ++r)
            madd[tt][r] = mneg[16 * tt + 4 * g + r];

    const float* qbase = img  + ((size_t)b * DHc + 8 * g) * Nc + c;
    float*       abase = attn + ((size_t)b * DHc + c) * Nc + 4 * g;  // Oᵀ store base
    float*       cbase = coeff + (size_t)b * Nc * Tc;

    const int ls_lo = c + 32 * (g & 1);
    const int sel   = g >> 1;

    // ---- preload Q for it=0 ----
    float qa[32], qb[32];
    {
        const float* qp = qbase + strip * 512 + wave * 16;
        #pragma unroll
        for (int u = 0; u < 32; ++u)
            qa[u] = qp[(size_t)((u >> 3) * 32 + (u & 7)) * Nc];
    }

    #pragma unroll 2
    for (int it = 0; it < 8; ++it) {
        const int n0 = strip * 512 + (it * 4 + wave) * 16;

        // ---- issue next iteration's Q loads (latency hidden under compute) ----
        if (it < 7) {
            const float* qpn = qbase + n0 + 64;
            #pragma unroll
            for (int u = 0; u < 32; ++u)
                qb[u] = qpn[(size_t)((u >> 3) * 32 + (u & 7)) * Nc];
        }

        // ---- split current Q into f16 hi/lo fragments ----
        v8hf Qh[4], Ql[4];
        #pragma unroll
        for (int ks = 0; ks < 4; ++ks)
            #pragma unroll
            for (int j = 0; j < 8; ++j) {
                float qv = qa[ks * 8 + j];
                _Float16 h = (_Float16)qv;
                Qh[ks][j] = h;
                Ql[ks][j] = (_Float16)(qv - (float)h);
            }

        // ---- Sᵀ = Vᵀ·Q : 2 t-tiles × 4 k-steps × 3 split terms ----
        v4f Sh[2], Sl[2];
        #pragma unroll
        for (int tt = 0; tt < 2; ++tt) {
            Sh[tt] = (v4f){0.f, 0.f, 0.f, 0.f};
            Sl[tt] = (v4f){0.f, 0.f, 0.f, 0.f};
        }
        #pragma unroll
        for (int tt = 0; tt < 2; ++tt) {
            const int rowbase = (16 * tt + c) * VT_LD + 8 * g;
            #pragma unroll
            for (int ks = 0; ks < 4; ++ks) {
                v8hf va = *(const v8hf*)&VTh[rowbase + ks * 32];
                v8hf vl = *(const v8hf*)&VTl[rowbase + ks * 32];
                Sh[tt] = __builtin_amdgcn_mfma_f32_16x16x32_f16(va, Qh[ks], Sh[tt], 0, 0, 0);
                Sl[tt] = __builtin_amdgcn_mfma_f32_16x16x32_f16(va, Ql[ks], Sl[tt], 0, 0, 0);
                Sl[tt] = __builtin_amdgcn_mfma_f32_16x16x32_f16(vl, Qh[ks], Sl[tt], 0, 0, 0);
            }
        }

        // ---- masked softmax over t ----
        float p0[4], p1[4];
        float m = -INFINITY;
        #pragma unroll
        for (int r = 0; r < 4; ++r) {
            p0[r] = Sh[0][r] + Sl[0][r] + madd[0][r];
            p1[r] = Sh[1][r] + Sl[1][r] + madd[1][r];
            m = fmaxf(m, fmaxf(p0[r], p1[r]));
        }
        m = fmaxf(m, __shfl_xor(m, 16));
        m = fmaxf(m, __shfl_xor(m, 32));
        float sum = 0.0f;
        #pragma unroll
        for (int r = 0; r < 4; ++r) {
            p0[r] = __expf(p0[r] - m); sum += p0[r];
            p1[r] = __expf(p1[r] - m); sum += p1[r];
        }
        sum += __shfl_xor(sum, 16);
        sum += __shfl_xor(sum, 32);
        const float inv = 1.0f / sum;
        #pragma unroll
        for (int r = 0; r < 4; ++r) { p0[r] *= inv; p1[r] *= inv; }

        // ---- coefficients [B,N,T] ----
        float* cp = cbase + (size_t)(n0 + c) * Tc + 4 * g;
        *(float4*)cp        = make_float4(p0[0], p0[1], p0[2], p0[3]);
        *(float4*)(cp + 16) = make_float4(p1[0], p1[1], p1[2], p1[3]);

        // ---- relayout P: lane (c,g) gets t = 8g+j for pixel c ----
        v8hf Pb;
        #pragma unroll
        for (int r = 0; r < 4; ++r) {
            v2hf h2; h2[0] = (_Float16)p0[r]; h2[1] = (_Float16)p1[r];
            int u   = __builtin_bit_cast(int, h2);
            int ulo = __shfl(u, ls_lo);
            int uhi = __shfl(u, ls_lo + 16);
            Pb[r]     = pick_half(ulo, sel);
            Pb[4 + r] = pick_half(uhi, sel);
        }

        // ---- Oᵀ = Pᵀ·Vhᵀ : C/D row = pixel 4g+r, col = k=16mt+c → dwordx4 ----
        #pragma unroll
        for (int mt = 0; mt < 8; ++mt) {
            v8hf vb2 = *(const v8hf*)&VPh[(16 * mt + c) * VP_LD + 8 * g];
            v4f o = (v4f){0.f, 0.f, 0.f, 0.f};
            o = __builtin_amdgcn_mfma_f32_16x16x32_f16(Pb, vb2, o, 0, 0, 0);
            float* ap = abase + (size_t)(16 * mt) * Nc + n0;
            *(float4*)ap = make_float4(o[0], o[1], o[2], o[3]);
        }

        // ---- rotate prefetched Q ----
        if (it < 7) {
            #pragma unroll
            for (int u = 0; u < 32; ++u) qa[u] = qb[u];
        }
    }
}

extern "C" void kernel_launch(void* const* d_in, const int* in_sizes, int n_in,
                              void* d_out, int out_size, void* d_ws, size_t ws_size,
                              hipStream_t stream)
{
    const float* wf   = (const float*)d_in[0];  // [B,D,T]
    const float* img  = (const float*)d_in[1];  // [B,Dh,H,W]
    const int*   msk  = (const int*)d_in[2];    // [B,T]
    const float* Wm   = (const float*)d_in[3];  // [Dh,D]
    const float* bias = (const float*)d_in[4];  // [Dh]

    float* attn  = (float*)d_out;                        // [B,Dh,N]
    float* coeff = attn + (size_t)Bc * DHc * Nc;         // [B,N,T]

    // workspace: three split-f16 buffers of B*Dh*T halves each (256 KB each)
    _Float16* vth = (_Float16*)d_ws;
    _Float16* vtl = vth + (size_t)Bc * DHc * Tc;
    _Float16* vph = vtl + (size_t)Bc * DHc * Tc;

    values_kernel<<<256, 256, 0, stream>>>(wf, Wm, bias, vth, vtl, vph);
    attn_kernel<<<Bc * 32, 256, 0, stream>>>(img, vth, vtl, vph, msk, attn, coeff);
}

// Round 4
// 533.070 us; speedup vs baseline: 1.2842x; 1.2842x over previous
//
#include <hip/hip_runtime.h>
#include <math.h>

// Problem constants (fixed by setup_inputs)
constexpr int Bc  = 32;     // batch
constexpr int Dc  = 256;    // word feature dim
constexpr int Tc  = 32;     // seq len
constexpr int DHc = 128;    // image feature dim
constexpr int Nc  = 16384;  // H*W = 128*128

typedef _Float16 v8hf __attribute__((ext_vector_type(8)));
typedef _Float16 v2hf __attribute__((ext_vector_type(2)));
typedef float    v4f  __attribute__((ext_vector_type(4)));

// ---------------------------------------------------------------------------
// Stage 1: V = W·wf_b + bias, emitted directly as split-f16 buffers:
//   vth [b][t][k] (f16 hi)   vtl [b][t][k] (f16 lo)   vph [b][k][t] (f16 hi)
// grid: 32 b × 8 k-blocks of 16 = 256 blocks, 256 threads.  (~10 µs)
// ---------------------------------------------------------------------------
__global__ __launch_bounds__(256) void values_kernel(
    const float* __restrict__ wf, const float* __restrict__ Wm,
    const float* __restrict__ bias,
    _Float16* __restrict__ vth, _Float16* __restrict__ vtl,
    _Float16* __restrict__ vph)
{
    __shared__ float wfs[Dc * Tc];        // 32 KB  [d][t]
    __shared__ float Ws[16 * 260];        // 16.6 KB, padded rows

    const int tid = threadIdx.x;
    const int b   = blockIdx.x >> 3;
    const int k0  = (blockIdx.x & 7) * 16;

    {   // stage wf[b]: 8192 floats, coalesced float4
        const float4* src = (const float4*)(wf + (size_t)b * Dc * Tc);
        float4* dst = (float4*)wfs;
        #pragma unroll
        for (int i = 0; i < 8; ++i) dst[tid + 256 * i] = src[tid + 256 * i];
    }
    {   // stage W rows k0..k0+15: 4096 floats
        #pragma unroll
        for (int i = 0; i < 4; ++i) {
            int f = tid + 256 * i;            // float4 index
            int row = f >> 6, d4 = f & 63;
            *(float4*)&Ws[row * 260 + 4 * d4] =
                *(const float4*)&Wm[(size_t)(k0 + row) * Dc + 4 * d4];
        }
    }
    __syncthreads();

    const int kl  = tid >> 4;          // 0..15
    const int tt0 = (tid & 15) * 2;    // even t
    const int k   = k0 + kl;

    float acc0 = bias[k], acc1 = acc0;
    #pragma unroll
    for (int d4 = 0; d4 < 64; ++d4) {
        const float4 w4 = *(const float4*)&Ws[kl * 260 + 4 * d4];
        #pragma unroll
        for (int j = 0; j < 4; ++j) {
            const float2 f2 = *(const float2*)&wfs[(4 * d4 + j) * Tc + tt0];
            const float wv = (j == 0) ? w4.x : (j == 1) ? w4.y : (j == 2) ? w4.z : w4.w;
            acc0 = fmaf(wv, f2.x, acc0);
            acc1 = fmaf(wv, f2.y, acc1);
        }
    }

    _Float16 vh0 = (_Float16)acc0, vh1 = (_Float16)acc1;
    _Float16 vl0 = (_Float16)(acc0 - (float)vh0);
    _Float16 vl1 = (_Float16)(acc1 - (float)vh1);

    {
        v2hf p; p[0] = vh0; p[1] = vh1;
        *(v2hf*)&vph[((size_t)b * DHc + k) * Tc + tt0] = p;
    }
    vth[((size_t)b * Tc + tt0)     * DHc + k] = vh0;
    vth[((size_t)b * Tc + tt0 + 1) * DHc + k] = vh1;
    vtl[((size_t)b * Tc + tt0)     * DHc + k] = vl0;
    vtl[((size_t)b * Tc + tt0 + 1) * DHc + k] = vl1;
}

__device__ __forceinline__ _Float16 pick_half(int u, int sel) {
    unsigned short s = (unsigned short)(sel ? (u >> 16) : u);
    return __builtin_bit_cast(_Float16, s);
}

// ---------------------------------------------------------------------------
// Stage 2 (MFMA): per 256-pixel strip of one batch (grid 2048 = 8 blocks/CU).
//  staging = pure uint4 copies of pre-split V
//  Sᵀ = Vᵀ·Q (f16 hi/lo 3-term split), in-register masked softmax,
//  P relayout via shuffles, Oᵀ = Pᵀ·Vhᵀ with dwordx4 stores.
// ---------------------------------------------------------------------------
__global__ __launch_bounds__(256) void attn_kernel(
    const float* __restrict__ img,
    const _Float16* __restrict__ vth, const _Float16* __restrict__ vtl,
    const _Float16* __restrict__ vph,
    const int* __restrict__ mask, float* __restrict__ attn,
    float* __restrict__ coeff)
{
    constexpr int VT_LD = 136;  // k-stride (halves); 272B rows → ≤2-way banks
    constexpr int VP_LD = 40;   // t-stride (halves); 80B rows  → ≤2-way banks
    __shared__ __align__(16) _Float16 VTh[Tc * VT_LD];
    __shared__ __align__(16) _Float16 VTl[Tc * VT_LD];
    __shared__ __align__(16) _Float16 VPh[DHc * VP_LD];
    __shared__ float mneg[Tc];              // total ~27.8 KB

    const int tid   = threadIdx.x;
    const int b     = blockIdx.x >> 6;      // 64 strips per batch
    const int strip = blockIdx.x & 63;

    {   // staging: pure copies (512 chunks of 16B per buffer)
        const uint4* sth = (const uint4*)(vth + (size_t)b * Tc * DHc);
        const uint4* stl = (const uint4*)(vtl + (size_t)b * Tc * DHc);
        const uint4* sph = (const uint4*)(vph + (size_t)b * DHc * Tc);
        #pragma unroll
        for (int i = 0; i < 2; ++i) {
            int cid = tid + 256 * i;
            int t = cid >> 4, cc = cid & 15;        // 16 chunks per 128-half row
            *(uint4*)&VTh[t * VT_LD + 8 * cc] = sth[cid];
            *(uint4*)&VTl[t * VT_LD + 8 * cc] = stl[cid];
            int kk = cid >> 2, c4 = cid & 3;        // 4 chunks per 32-half row
            *(uint4*)&VPh[kk * VP_LD + 8 * c4] = sph[cid];
        }
        if (tid < Tc) mneg[tid] = mask[b * Tc + tid] ? -INFINITY : 0.0f;
    }
    __syncthreads();

    const int lane = tid & 63;
    const int wave = tid >> 6;
    const int c    = lane & 15;   // pixel column within 16-px tile
    const int g    = lane >> 4;   // lane group

    float madd[2][4];
    #pragma unroll
    for (int tt = 0; tt < 2; ++tt)
        #pragma unroll
        for (int r = 0; r < 4; ++r)
            madd[tt][r] = mneg[16 * tt + 4 * g + r];

    const float* qbase = img  + ((size_t)b * DHc + 8 * g) * Nc + c;
    float*       abase = attn + ((size_t)b * DHc + c) * Nc + 4 * g;  // Oᵀ store base
    float*       cbase = coeff + (size_t)b * Nc * Tc;

    const int ls_lo = c + 32 * (g & 1);
    const int sel   = g >> 1;

    #pragma unroll 2
    for (int it = 0; it < 4; ++it) {
        const int n0 = strip * 256 + (it * 4 + wave) * 16;

        // ---- load Q columns (lane = pixel c, k = ks*32+8g+j), split hi/lo ----
        const float* qp = qbase + n0;
        v8hf Qh[4], Ql[4];
        #pragma unroll
        for (int ks = 0; ks < 4; ++ks)
            #pragma unroll
            for (int j = 0; j < 8; ++j) {
                float qv = qp[(size_t)(ks * 32 + j) * Nc];
                _Float16 h = (_Float16)qv;
                Qh[ks][j] = h;
                Ql[ks][j] = (_Float16)(qv - (float)h);
            }

        // ---- Sᵀ = Vᵀ·Q : 2 t-tiles × 4 k-steps × 3 split terms ----
        v4f Sh[2], Sl[2];
        #pragma unroll
        for (int tt = 0; tt < 2; ++tt) {
            Sh[tt] = (v4f){0.f, 0.f, 0.f, 0.f};
            Sl[tt] = (v4f){0.f, 0.f, 0.f, 0.f};
        }
        #pragma unroll
        for (int tt = 0; tt < 2; ++tt) {
            const int rowbase = (16 * tt + c) * VT_LD + 8 * g;
            #pragma unroll
            for (int ks = 0; ks < 4; ++ks) {
                v8hf va = *(const v8hf*)&VTh[rowbase + ks * 32];
                v8hf vl = *(const v8hf*)&VTl[rowbase + ks * 32];
                Sh[tt] = __builtin_amdgcn_mfma_f32_16x16x32_f16(va, Qh[ks], Sh[tt], 0, 0, 0);
                Sl[tt] = __builtin_amdgcn_mfma_f32_16x16x32_f16(va, Ql[ks], Sl[tt], 0, 0, 0);
                Sl[tt] = __builtin_amdgcn_mfma_f32_16x16x32_f16(vl, Qh[ks], Sl[tt], 0, 0, 0);
            }
        }

        // ---- masked softmax over t ----
        float p0[4], p1[4];
        float m = -INFINITY;
        #pragma unroll
        for (int r = 0; r < 4; ++r) {
            p0[r] = Sh[0][r] + Sl[0][r] + madd[0][r];
            p1[r] = Sh[1][r] + Sl[1][r] + madd[1][r];
            m = fmaxf(m, fmaxf(p0[r], p1[r]));
        }
        m = fmaxf(m, __shfl_xor(m, 16));
        m = fmaxf(m, __shfl_xor(m, 32));
        float sum = 0.0f;
        #pragma unroll
        for (int r = 0; r < 4; ++r) {
            p0[r] = __expf(p0[r] - m); sum += p0[r];
            p1[r] = __expf(p1[r] - m); sum += p1[r];
        }
        sum += __shfl_xor(sum, 16);
        sum += __shfl_xor(sum, 32);
        const float inv = 1.0f / sum;
        #pragma unroll
        for (int r = 0; r < 4; ++r) { p0[r] *= inv; p1[r] *= inv; }

        // ---- coefficients [B,N,T] ----
        float* cp = cbase + (size_t)(n0 + c) * Tc + 4 * g;
        *(float4*)cp        = make_float4(p0[0], p0[1], p0[2], p0[3]);
        *(float4*)(cp + 16) = make_float4(p1[0], p1[1], p1[2], p1[3]);

        // ---- relayout P: lane (c,g) gets t = 8g+j for pixel c ----
        v8hf Pb;
        #pragma unroll
        for (int r = 0; r < 4; ++r) {
            v2hf h2; h2[0] = (_Float16)p0[r]; h2[1] = (_Float16)p1[r];
            int u   = __builtin_bit_cast(int, h2);
            int ulo = __shfl(u, ls_lo);
            int uhi = __shfl(u, ls_lo + 16);
            Pb[r]     = pick_half(ulo, sel);
            Pb[4 + r] = pick_half(uhi, sel);
        }

        // ---- Oᵀ = Pᵀ·Vhᵀ : C/D row = pixel 4g+r, col = k=16mt+c → dwordx4 ----
        #pragma unroll
        for (int mt = 0; mt < 8; ++mt) {
            v8hf vb2 = *(const v8hf*)&VPh[(16 * mt + c) * VP_LD + 8 * g];
            v4f o = (v4f){0.f, 0.f, 0.f, 0.f};
            o = __builtin_amdgcn_mfma_f32_16x16x32_f16(Pb, vb2, o, 0, 0, 0);
            float* ap = abase + (size_t)(16 * mt) * Nc + n0;
            *(float4*)ap = make_float4(o[0], o[1], o[2], o[3]);
        }
    }
}

extern "C" void kernel_launch(void* const* d_in, const int* in_sizes, int n_in,
                              void* d_out, int out_size, void* d_ws, size_t ws_size,
                              hipStream_t stream)
{
    const float* wf   = (const float*)d_in[0];  // [B,D,T]
    const float* img  = (const float*)d_in[1];  // [B,Dh,H,W]
    const int*   msk  = (const int*)d_in[2];    // [B,T]
    const float* Wm   = (const float*)d_in[3];  // [Dh,D]
    const float* bias = (const float*)d_in[4];  // [Dh]

    float* attn  = (float*)d_out;                        // [B,Dh,N]
    float* coeff = attn + (size_t)Bc * DHc * Nc;         // [B,N,T]

    // workspace: three split-f16 buffers of B*Dh*T halves each (256 KB each)
    _Float16* vth = (_Float16*)d_ws;
    _Float16* vtl = vth + (size_t)Bc * DHc * Tc;
    _Float16* vph = vtl + (size_t)Bc * DHc * Tc;

    values_kernel<<<256, 256, 0, stream>>>(wf, Wm, bias, vth, vtl, vph);
    attn_kernel<<<Bc * 64, 256, 0, stream>>>(img, vth, vtl, vph, msk, attn, coeff);
}